// Round 11
// baseline (34.946 us; speedup 1.0000x reference)
//
#include <hip/hip_runtime.h>

#define SEQ 2048
#define DIM 6
#define NW 8                 // waves per block
#define BLOCK (NW * 64)
#define VROW 2056            // padded V^T row stride in elements (2048 + 8)

typedef _Float16 half4F __attribute__((ext_vector_type(4)));
typedef short bf16x4 __attribute__((ext_vector_type(4)));
typedef float f32x4 __attribute__((ext_vector_type(4)));

union FragU { uint2 u; half4F h; bf16x4 b; };

__device__ __forceinline__ unsigned pkh(float a, float b) {
    return __builtin_bit_cast(unsigned, __builtin_amdgcn_cvt_pkrtz(a, b));
}

// bf16 round-to-nearest-even via integer rounding (values are finite, non-NaN).
__device__ __forceinline__ unsigned bf16rn(float x) {
    unsigned u = __builtin_bit_cast(unsigned, x);
    return (u + 0x7FFFu + ((u >> 16) & 1u)) >> 16;
}
__device__ __forceinline__ unsigned pkbf(float a, float b) {
    return bf16rn(a) | (bf16rn(b) << 16);
}

__device__ __forceinline__ f32x4 mfma_bf16_(bf16x4 a, bf16x4 b, f32x4 c) {
#if __has_builtin(__builtin_amdgcn_mfma_f32_16x16x16bf16_1k)
    return __builtin_amdgcn_mfma_f32_16x16x16bf16_1k(a, b, c, 0, 0, 0);
#else
    f32x4 d;
    asm("v_mfma_f32_16x16x16_bf16 %0, %1, %2, %3"
        : "=v"(d) : "v"(a), "v"(b), "v"(c));
    return d;
#endif
}

// K' [t][8] fp16: {k0..k5 (x log2e), bias (0 / -1024), unused}
// Vt [7][VROW] bf16: rows 0..5 = V dims (transposed), row 6 = ones (denominator)
// QK MFMA (f16): A=K'-tile, B=Q' -> D[t_loc][s] = log2e*score + bias
// PV MFMA (bf16): A=exp2(D) (same lane mapping), B=Vt-tile -> C[s][d], col6=denom
// No max pass: p = exp2(arg) <= 2^~35, bf16/f32 range is plenty.

__launch_bounds__(BLOCK, 4)
__global__ void attn_mfma(const float* __restrict__ X,
                          const int* __restrict__ mask,
                          const float* __restrict__ Wq, const float* __restrict__ bq,
                          const float* __restrict__ Wk, const float* __restrict__ bk,
                          const float* __restrict__ Wv, const float* __restrict__ bv,
                          float* __restrict__ out) {
    __shared__ __align__(16) __fp16 Ksm[SEQ * 8];
    __shared__ __align__(16) unsigned short Vtsm[7 * VROW];

    const int b = blockIdx.x >> 4;   // 16 blocks per batch
    const int tid = threadIdx.x;
    const float* Xb = X + (size_t)b * SEQ * DIM;
    const int* mb = mask + (size_t)b * SEQ;
    const float L2E = 1.44269504088896f;

    // ---- Stage K' (fp16) and V^T (bf16) for this batch ----
#pragma unroll
    for (int i = 0; i < SEQ / BLOCK; ++i) {
        const int t = tid + i * BLOCK;
        const float2* xp = reinterpret_cast<const float2*>(Xb + t * DIM);
        float2 x01 = xp[0], x23 = xp[1], x45 = xp[2];
        float x[DIM] = {x01.x, x01.y, x23.x, x23.y, x45.x, x45.y};
        float kk[DIM], vv[DIM];
#pragma unroll
        for (int r = 0; r < DIM; ++r) {
            float k = bk[r], v = bv[r];
#pragma unroll
            for (int c = 0; c < DIM; ++c) {
                k = fmaf(Wk[r * DIM + c], x[c], k);
                v = fmaf(Wv[r * DIM + c], x[c], v);
            }
            kk[r] = k * L2E;
            vv[r] = v;
        }
        const float bias = (mb[t] == 0) ? -1024.0f : 0.0f;
        uint4 kw;
        kw.x = pkh(kk[0], kk[1]);
        kw.y = pkh(kk[2], kk[3]);
        kw.z = pkh(kk[4], kk[5]);
        kw.w = pkh(bias, 0.0f);
        *reinterpret_cast<uint4*>(&Ksm[t * 8]) = kw;
#pragma unroll
        for (int r = 0; r < DIM; ++r)
            Vtsm[r * VROW + t] = (unsigned short)bf16rn(vv[r]);
        Vtsm[6 * VROW + t] = 0x3F80u;  // bf16 1.0
    }
    __syncthreads();

    // ---- Per-wave: one 16-row s-tile ----
    const int lane = tid & 63, wid = tid >> 6;
    const int s0 = ((blockIdx.x & 15) * NW + wid) * 16;
    const int r15 = lane & 15, g = lane >> 4;
    const int s = s0 + r15;

    // Q' projection for row s (4 lane-copies compute the same row)
    float qq[DIM], biasm;
    {
        const float2* xp = reinterpret_cast<const float2*>(Xb + s * DIM);
        float2 x01 = xp[0], x23 = xp[1], x45 = xp[2];
        float x[DIM] = {x01.x, x01.y, x23.x, x23.y, x45.x, x45.y};
        const bool rm = (mb[s] == 0);  // masked row -> p=1 over all t (uniform mean)
#pragma unroll
        for (int r = 0; r < DIM; ++r) {
            float q = bq[r];
#pragma unroll
            for (int c = 0; c < DIM; ++c) q = fmaf(Wq[r * DIM + c], x[c], q);
            qq[r] = rm ? 0.0f : q;
        }
        biasm = rm ? 0.0f : 1.0f;
    }

    // B-fragment: lane g holds Q'[s][g*4 .. g*4+3]; k-slots 8..15 are zero.
    FragU qf;
    qf.u.x = (g == 0) ? pkh(qq[0], qq[1]) : (g == 1) ? pkh(qq[4], qq[5]) : 0u;
    qf.u.y = (g == 0) ? pkh(qq[2], qq[3]) : (g == 1) ? pkh(biasm, 0.0f) : 0u;

    const f32x4 zero4 = {0.0f, 0.0f, 0.0f, 0.0f};

    // ---- Single pass: QK -> exp2 -> PV (numerators + denominator) ----
    f32x4 acc = zero4;
    {
        const int dcl = (r15 < 6) ? r15 : 6;  // cols 7..15 alias ones row (unused)
        int kidx = r15 * 8 + (g & 1) * 4;
        int vidx = dcl * VROW + g * 4;
#pragma unroll 2
        for (int tt = 0; tt < SEQ / 16; ++tt) {
            half4F kf = *reinterpret_cast<const half4F*>(&Ksm[kidx]);
            f32x4 d = __builtin_amdgcn_mfma_f32_16x16x16f16(kf, qf.h, zero4, 0, 0, 0);
            FragU pa;  // P in PV A-layout (same lane holds same (s, t_loc))
            pa.u.x = pkbf(__builtin_amdgcn_exp2f(d[0]), __builtin_amdgcn_exp2f(d[1]));
            pa.u.y = pkbf(__builtin_amdgcn_exp2f(d[2]), __builtin_amdgcn_exp2f(d[3]));
            bf16x4 vf = *reinterpret_cast<const bf16x4*>(&Vtsm[vidx]);
            acc = mfma_bf16_(pa.b, vf, acc);
            kidx += 128;
            vidx += 16;
        }
    }

    // ---- Epilogue: divide numerators (cols 0..5) by denominator (col 6) ----
    const int srcl = (lane & 48) | 6;
#pragma unroll
    for (int r = 0; r < 4; ++r) {
        const float dnm = __shfl(acc[r], srcl);
        const float val = acc[r] * __builtin_amdgcn_rcpf(dnm);
        if (r15 < 6) {
            out[((size_t)b * SEQ + s0 + g * 4 + r) * DIM + r15] = val;
        }
    }
}

extern "C" void kernel_launch(void* const* d_in, const int* in_sizes, int n_in,
                              void* d_out, int out_size, void* d_ws, size_t ws_size,
                              hipStream_t stream) {
    const float* X  = (const float*)d_in[0];
    const int* mask = (const int*)d_in[1];
    const float* Wq = (const float*)d_in[2];
    const float* bq = (const float*)d_in[3];
    const float* Wk = (const float*)d_in[4];
    const float* bk = (const float*)d_in[5];
    const float* Wv = (const float*)d_in[6];
    const float* bv = (const float*)d_in[7];
    float* out = (float*)d_out;

    const int B = in_sizes[0] / (SEQ * DIM);

    dim3 grid(B * 16);  // 16 blocks per batch, 8 s-tiles (waves) per block
    attn_mfma<<<grid, BLOCK, 0, stream>>>(X, mask, Wq, bq, Wk, bk, Wv, bv, out);
}